// Round 7
// baseline (204.962 us; speedup 1.0000x reference)
//
#include <hip/hip_runtime.h>

#define NN 50000
#define NE 800000
#define DF 128
#define NG 64
#define NC 10
#define NBK 98            // ceil(NN/512) coarse buckets (dst>>9)
#define PART_CHUNK 4096
#define PART_GRID 196     // 196*4096 >= 800000
#define ACAP 12288        // arena capacity per bucket (avg 8163, max ~8600)
#define FINE_CAP 12288
#define RT 136            // h staging row stride (ushorts)

typedef short bf16x8 __attribute__((ext_vector_type(8)));
typedef float f32x4  __attribute__((ext_vector_type(4)));

__device__ __forceinline__ void atomAddF(float* p, float v) {
  __hip_atomic_fetch_add(p, v, __ATOMIC_RELAXED, __HIP_MEMORY_SCOPE_AGENT);
}
__device__ __forceinline__ float b2f(unsigned short u) {
  union { unsigned int i; float f; } v; v.i = (unsigned int)u << 16; return v.f;
}
__device__ __forceinline__ unsigned int f2b(float f) {
  unsigned int i = __float_as_uint(f);
  return (i + 0x7fffu + ((i >> 16) & 1u)) >> 16;
}

// ======== cast x (fp32) -> xb (bf16) ========
__global__ __launch_bounds__(256) void k_cast(const float* __restrict__ x,
                                              unsigned short* __restrict__ xb)
{
  const int i = blockIdx.x * 256 + threadIdx.x;
  if (i * 4 >= NN * DF) return;
  const float4 v = reinterpret_cast<const float4*>(x)[i];
  uint2 o;
  o.x = f2b(v.x) | (f2b(v.y) << 16);
  o.y = f2b(v.z) | (f2b(v.w) << 16);
  reinterpret_cast<uint2*>(xb)[i] = o;
}

// ======== transpose + cast weights: Wt[mat][n][k] = bf16(W[mat][k][n]) ========
__global__ __launch_bounds__(256) void k_prepw(const float* __restrict__ W0,
                                               const float* __restrict__ W1,
                                               const float* __restrict__ W2,
                                               const float* __restrict__ W3,
                                               unsigned short* __restrict__ Wt)
{
  const int o = blockIdx.x * 256 + threadIdx.x;
  if (o >= 4 * 2048) return;
  const int mat = o >> 11;
  const float* W = (mat == 0) ? W0 : (mat == 1) ? W1 : (mat == 2) ? W2 : W3;
  const int rem = o & 2047;
  const int n  = rem >> 4;
  const int k0 = (rem & 15) * 8;
  unsigned int u[8];
#pragma unroll
  for (int j = 0; j < 8; ++j) u[j] = f2b(W[(size_t)(k0 + j) * DF + n]);
  uint4 p;
  p.x = u[0] | (u[1] << 16);
  p.y = u[2] | (u[3] << 16);
  p.z = u[4] | (u[5] << 16);
  p.w = u[6] | (u[7] << 16);
  *reinterpret_cast<uint4*>(Wt + (size_t)mat * DF * DF + (size_t)n * DF + k0) = p;
}

// ---- partition edges into NBK bucket arenas (self-allocating) ----
// pack = (bucket<<25) | (dstlocal<<16) | src
__global__ __launch_bounds__(256) void k_part(const int* __restrict__ src,
                                              const int* __restrict__ dst,
                                              int* __restrict__ cnt_b,
                                              unsigned int* __restrict__ arena)
{
  __shared__ unsigned int stage[PART_CHUNK];
  __shared__ int lhist[128], lcnt[128], lcur[128], gbase[128];
  const int tid = threadIdx.x;
  const int e0  = blockIdx.x * PART_CHUNK;
  const int nE  = min(PART_CHUNK, NE - e0);

  for (int i = tid; i < 128; i += 256) lhist[i] = 0;
  __syncthreads();

  unsigned int pk[16];
  int bk[16];
#pragma unroll
  for (int i = 0; i < 16; ++i) {
    const int e = e0 + i * 256 + tid;
    if (e < NE) {
      const int d = dst[e];
      const int s = src[e];
      const int b = d >> 9;
      bk[i] = b;
      pk[i] = ((unsigned int)b << 25) | ((unsigned int)(d & 511) << 16) | (unsigned int)s;
      atomicAdd(&lhist[b], 1);
    } else {
      bk[i] = -1;
    }
  }
  __syncthreads();
  for (int i = tid; i < 128; i += 256) lcnt[i] = lhist[i];
  __syncthreads();
  for (int off = 1; off < 128; off <<= 1) {
    int v = 0;
    if (tid < 128 && tid >= off) v = lhist[tid - off];
    __syncthreads();
    if (tid < 128) lhist[tid] += v;
    __syncthreads();
  }
  if (tid < 128) lcur[tid] = lhist[tid] - lcnt[tid];
  __syncthreads();
#pragma unroll
  for (int i = 0; i < 16; ++i) {
    if (bk[i] >= 0) {
      const int pos = atomicAdd(&lcur[bk[i]], 1);
      stage[pos] = pk[i];
    }
  }
  __syncthreads();
  if (tid < NBK) {
    const int c = lcnt[tid];
    if (c > 0) gbase[tid] = atomicAdd(&cnt_b[tid], c);
  }
  __syncthreads();
  for (int idx = tid; idx < nE; idx += 256) {
    const unsigned int p = stage[idx];
    const int b = (int)(p >> 25);
    const int loff = lhist[b] - lcnt[b];
    arena[(size_t)b * ACAP + gbase[b] + (idx - loff)] = p;
  }
}

// ---- scan the 98 bucket counts -> bucket bases; rs[NN] ----
__global__ __launch_bounds__(128) void k_bscan(const int* __restrict__ cnt_b,
                                               int* __restrict__ base_b,
                                               int* __restrict__ rs)
{
  __shared__ int sm[128];
  const int t = threadIdx.x;
  const int v = (t < NBK) ? cnt_b[t] : 0;
  sm[t] = v;
  __syncthreads();
  for (int off = 1; off < 128; off <<= 1) {
    int u = (t >= off) ? sm[t - off] : 0;
    __syncthreads();
    sm[t] += u;
    __syncthreads();
  }
  base_b[t] = sm[t] - v;
  if (t == NBK - 1) rs[NN] = sm[t];   // = NE
}

// ---- per bucket: counting sort by (dstlocal, src>>13) -> rs, es(u16) ----
// key = dstlocal*8 + src_chunk; src chunks of 8192 rows (2.1 MB windows)
// so every node's edge list is ordered by src-chunk -> gather phase-locality.
__global__ __launch_bounds__(256) void k_fine(const unsigned int* __restrict__ arena,
                                              const int* __restrict__ cnt_b,
                                              const int* __restrict__ base_b,
                                              int* __restrict__ rs,
                                              unsigned short* __restrict__ es)
{
  __shared__ unsigned short les[FINE_CAP];   // 24 KB
  __shared__ int bins[4096];                 // 16 KB
  __shared__ int partials[256];
  const int tid   = threadIdx.x;
  const int b     = blockIdx.x;
  const int cnt   = cnt_b[b];
  const int wbase = base_b[b];
  const int nbase = b << 9;
  const int nwin  = min(512, NN - nbase);
  const unsigned int* ap = arena + (size_t)b * ACAP;

  for (int i = tid; i < 4096; i += 256) bins[i] = 0;
  __syncthreads();
  for (int idx = tid; idx < cnt; idx += 256) {
    const unsigned int p = ap[idx];
    const int key = (int)(((p >> 16) & 511) << 3) | (int)((p & 0xffffu) >> 13);
    atomicAdd(&bins[key], 1);
  }
  __syncthreads();
  // scan 4096 bins: 16 per thread
  const int b16 = tid * 16;
  int sum = 0;
#pragma unroll
  for (int k = 0; k < 16; ++k) sum += bins[b16 + k];
  partials[tid] = sum;
  __syncthreads();
  for (int off = 1; off < 256; off <<= 1) {
    int u = (tid >= off) ? partials[tid - off] : 0;
    __syncthreads();
    partials[tid] += u;
    __syncthreads();
  }
  int run = partials[tid] - sum;   // exclusive base for this thread's 16 bins
#pragma unroll
  for (int k = 0; k < 16; ++k) {
    const int v = bins[b16 + k];
    bins[b16 + k] = run;
    run += v;
  }
  __syncthreads();
  for (int i = tid; i < nwin; i += 256) rs[nbase + i] = wbase + bins[i << 3];
  __syncthreads();
  if (cnt <= FINE_CAP) {
    for (int idx = tid; idx < cnt; idx += 256) {
      const unsigned int p = ap[idx];
      const int key = (int)(((p >> 16) & 511) << 3) | (int)((p & 0xffffu) >> 13);
      const int pos = atomicAdd(&bins[key], 1);
      les[pos] = (unsigned short)(p & 0xffffu);
    }
    __syncthreads();
    for (int i = tid; i < cnt; i += 256) es[wbase + i] = les[i];
  } else {   // statistically unreachable fallback
    for (int idx = tid; idx < cnt; idx += 256) {
      const unsigned int p = ap[idx];
      const int key = (int)(((p >> 16) & 511) << 3) | (int)((p & 0xffffu) >> 13);
      const int pos = atomicAdd(&bins[key], 1);
      es[wbase + pos] = (unsigned short)(p & 0xffffu);
    }
  }
}

// ======== gather-aggregate (bf16): out[i] = feat[i] + sum_j feat[es_j] ========
// edge lists are src-chunk-ordered -> all waves read the same ~2MB window at a time
__global__ __launch_bounds__(256) void k_gather(const unsigned short* __restrict__ feat,
                                                unsigned short* __restrict__ outp,
                                                const int* __restrict__ rs,
                                                const unsigned short* __restrict__ es)
{
  const int wid  = (blockIdx.x * 256 + threadIdx.x) >> 6;
  const int lane = threadIdx.x & 63;
  if (wid >= NN) return;
  const int beg = rs[wid];
  const int end = rs[wid + 1];
  const int off = lane * 2;

  const unsigned int self = *reinterpret_cast<const unsigned int*>(feat + (size_t)wid * DF + off);
  float ax = b2f(self & 0xffff), ay = b2f(self >> 16);
  int j = beg;
  while (j < end && (j & 3)) {
    const int s = es[j];
    const unsigned int u = *reinterpret_cast<const unsigned int*>(feat + (size_t)s * DF + off);
    ax += b2f(u & 0xffff);
    ay += b2f(u >> 16);
    ++j;
  }
  for (; j + 3 < end; j += 4) {
    const uint2 e4 = *reinterpret_cast<const uint2*>(es + j);
    const int s0 = (int)(e4.x & 0xffffu), s1 = (int)(e4.x >> 16);
    const int s2 = (int)(e4.y & 0xffffu), s3 = (int)(e4.y >> 16);
    const unsigned int u0 = *reinterpret_cast<const unsigned int*>(feat + (size_t)s0 * DF + off);
    const unsigned int u1 = *reinterpret_cast<const unsigned int*>(feat + (size_t)s1 * DF + off);
    const unsigned int u2 = *reinterpret_cast<const unsigned int*>(feat + (size_t)s2 * DF + off);
    const unsigned int u3 = *reinterpret_cast<const unsigned int*>(feat + (size_t)s3 * DF + off);
    ax += b2f(u0 & 0xffff) + b2f(u1 & 0xffff) + b2f(u2 & 0xffff) + b2f(u3 & 0xffff);
    ay += b2f(u0 >> 16)    + b2f(u1 >> 16)    + b2f(u2 >> 16)    + b2f(u3 >> 16);
  }
  for (; j < end; ++j) {
    const int s = es[j];
    const unsigned int u = *reinterpret_cast<const unsigned int*>(feat + (size_t)s * DF + off);
    ax += b2f(u & 0xffff);
    ay += b2f(u >> 16);
  }
  const unsigned int o = f2b(ax) | (f2b(ay) << 16);
  *reinterpret_cast<unsigned int*>(outp + (size_t)wid * DF + off) = o;
}

// ======== fused double GEMM: out = relu(relu(A@Wa+ba)@Wb+bb), bf16 MFMA ========
__global__ __launch_bounds__(256) void k_gemm2(const unsigned short* __restrict__ Ab,
                                               const unsigned short* __restrict__ Wta,
                                               const float* __restrict__ ba,
                                               const unsigned short* __restrict__ Wtb,
                                               const float* __restrict__ bb,
                                               unsigned short* __restrict__ outb, int M)
{
  __shared__ unsigned short WbL[128 * 128];     // 32 KB, rotated: [n][(kb+n)&15]
  __shared__ unsigned short hL[4][16 * RT];
  const int tid  = threadIdx.x;
  const int lane = tid & 63;
  const int w    = tid >> 6;
  const int col  = lane & 15;
  const int kq   = lane >> 4;

  for (int i = tid; i < 2048; i += 256) {
    const int n = i >> 4, kb = i & 15;
    const int kbp = (kb + n) & 15;
    *reinterpret_cast<uint4*>(&WbL[n * 128 + kbp * 8]) =
        *reinterpret_cast<const uint4*>(&Wtb[(size_t)n * 128 + kb * 8]);
  }

  bf16x8 wfa[8][4];
#pragma unroll
  for (int nf = 0; nf < 8; ++nf)
#pragma unroll
    for (int s = 0; s < 4; ++s)
      wfa[nf][s] = *reinterpret_cast<const bf16x8*>(
          Wta + (size_t)(nf * 16 + col) * DF + s * 32 + kq * 8);

  __syncthreads();

  unsigned short* hw = &hL[w][0];
  const int rbase = blockIdx.x * 256;

  int m = rbase + w * 16 + col;
  int mld = (m < M) ? m : (M - 1);
  bf16x8 bc[4];
#pragma unroll
  for (int s = 0; s < 4; ++s)
    bc[s] = *reinterpret_cast<const bf16x8*>(Ab + (size_t)mld * DF + s * 32 + kq * 8);

#pragma unroll
  for (int t = 0; t < 4; ++t) {
    bf16x8 bn[4];
    if (t < 3) {
      const int m2 = rbase + (t + 1) * 64 + w * 16 + col;
      const int mld2 = (m2 < M) ? m2 : (M - 1);
#pragma unroll
      for (int s = 0; s < 4; ++s)
        bn[s] = *reinterpret_cast<const bf16x8*>(Ab + (size_t)mld2 * DF + s * 32 + kq * 8);
    }
    f32x4 acc[8];
#pragma unroll
    for (int nf = 0; nf < 8; ++nf) acc[nf] = (f32x4){0.f, 0.f, 0.f, 0.f};
#pragma unroll
    for (int s = 0; s < 4; ++s)
#pragma unroll
      for (int nf = 0; nf < 8; ++nf)
        acc[nf] = __builtin_amdgcn_mfma_f32_16x16x32_bf16(wfa[nf][s], bc[s], acc[nf], 0, 0, 0);
#pragma unroll
    for (int nf = 0; nf < 8; ++nf) {
      const float4 bv = *reinterpret_cast<const float4*>(ba + nf * 16 + kq * 4);
      uint2 pk;
      pk.x = f2b(fmaxf(acc[nf][0] + bv.x, 0.f)) | (f2b(fmaxf(acc[nf][1] + bv.y, 0.f)) << 16);
      pk.y = f2b(fmaxf(acc[nf][2] + bv.z, 0.f)) | (f2b(fmaxf(acc[nf][3] + bv.w, 0.f)) << 16);
      *reinterpret_cast<uint2*>(&hw[col * RT + nf * 16 + kq * 4]) = pk;
    }
    asm volatile("s_waitcnt lgkmcnt(0)" ::: "memory");
    __builtin_amdgcn_sched_barrier(0);
    f32x4 acc2[8];
#pragma unroll
    for (int nf = 0; nf < 8; ++nf) acc2[nf] = (f32x4){0.f, 0.f, 0.f, 0.f};
#pragma unroll
    for (int s = 0; s < 4; ++s) {
      const bf16x8 hb = *reinterpret_cast<const bf16x8*>(&hw[col * RT + s * 32 + kq * 8]);
#pragma unroll
      for (int nf = 0; nf < 8; ++nf) {
        const int kbp = (s * 4 + kq + col) & 15;
        const bf16x8 wb = *reinterpret_cast<const bf16x8*>(&WbL[(nf * 16 + col) * 128 + kbp * 8]);
        acc2[nf] = __builtin_amdgcn_mfma_f32_16x16x32_bf16(wb, hb, acc2[nf], 0, 0, 0);
      }
    }
    if (m < M) {
#pragma unroll
      for (int nf = 0; nf < 8; ++nf) {
        const float4 bv = *reinterpret_cast<const float4*>(bb + nf * 16 + kq * 4);
        ushort4 p;
        p.x = (unsigned short)f2b(fmaxf(acc2[nf][0] + bv.x, 0.f));
        p.y = (unsigned short)f2b(fmaxf(acc2[nf][1] + bv.y, 0.f));
        p.z = (unsigned short)f2b(fmaxf(acc2[nf][2] + bv.z, 0.f));
        p.w = (unsigned short)f2b(fmaxf(acc2[nf][3] + bv.w, 0.f));
        *reinterpret_cast<ushort4*>(outb + (size_t)m * DF + nf * 16 + kq * 4) = p;
      }
    }
#pragma unroll
    for (int s = 0; s < 4; ++s) bc[s] = bn[s];
    m = rbase + (t + 1) * 64 + w * 16 + col;
    mld = (m < M) ? m : (M - 1);
  }
}

// ======== segment-mean pooling ========
__global__ __launch_bounds__(256) void k_pool(const unsigned short* __restrict__ h,
                                              const int* __restrict__ batch,
                                              float* __restrict__ sums,
                                              int* __restrict__ cnts)
{
  const int wv   = (blockIdx.x * 256 + threadIdx.x) >> 6;
  const int lane = threadIdx.x & 63;
  const int n0 = wv * 32;
  if (n0 >= NN) return;
  const int n1 = min(n0 + 32, NN);
  const int off = lane * 2;

  const int gfirst = batch[n0];
  const int glast  = batch[n1 - 1];
  float ax = 0.f, ay = 0.f;

  if (gfirst == glast) {
#pragma unroll 4
    for (int i = n0; i < n1; ++i) {
      const unsigned int u = *reinterpret_cast<const unsigned int*>(h + (size_t)i * DF + off);
      ax += b2f(u & 0xffff);
      ay += b2f(u >> 16);
    }
    atomAddF(&sums[gfirst * DF + off],     ax);
    atomAddF(&sums[gfirst * DF + off + 1], ay);
    if (lane == 0) atomicAdd(&cnts[gfirst], n1 - n0);
  } else {
    int g = gfirst, cnt = 0;
    for (int i = n0; i < n1; ++i) {
      const int gi = batch[i];
      if (gi != g) {
        atomAddF(&sums[g * DF + off],     ax);
        atomAddF(&sums[g * DF + off + 1], ay);
        if (lane == 0) atomicAdd(&cnts[g], cnt);
        ax = 0.f; ay = 0.f; cnt = 0; g = gi;
      }
      const unsigned int u = *reinterpret_cast<const unsigned int*>(h + (size_t)i * DF + off);
      ax += b2f(u & 0xffff);
      ay += b2f(u >> 16);
      ++cnt;
    }
    atomAddF(&sums[g * DF + off],     ax);
    atomAddF(&sums[g * DF + off + 1], ay);
    if (lane == 0) atomicAdd(&cnts[g], cnt);
  }
}

// ======== head ========
__global__ __launch_bounds__(256) void k_head(const float* __restrict__ sums,
                                              const int* __restrict__ cnts,
                                              const float* __restrict__ Wfc,
                                              const float* __restrict__ bfc,
                                              float* __restrict__ out)
{
  for (int o = threadIdx.x; o < NG * NC; o += 256) {
    const int g = o / NC, c = o % NC;
    const float inv = 1.f / fmaxf((float)cnts[g], 1.f);
    float z = bfc[c];
    for (int k = 0; k < DF; ++k)
      z = fmaf(sums[g * DF + k] * inv, Wfc[k * NC + c], z);
    out[o] = 1.f / (1.f + expf(-z));
  }
}

extern "C" void kernel_launch(void* const* d_in, const int* in_sizes, int n_in,
                              void* d_out, int out_size, void* d_ws, size_t ws_size,
                              hipStream_t stream)
{
  const float* x   = (const float*)d_in[0];
  const int*   ei  = (const int*)d_in[1];
  const int* batch = (const int*)d_in[2];
  const float* W1a = (const float*)d_in[3];
  const float* b1a = (const float*)d_in[4];
  const float* W1b = (const float*)d_in[5];
  const float* b1b = (const float*)d_in[6];
  const float* W2a = (const float*)d_in[7];
  const float* b2a = (const float*)d_in[8];
  const float* W2b = (const float*)d_in[9];
  const float* b2b = (const float*)d_in[10];
  const float* Wfc = (const float*)d_in[11];
  const float* bfc = (const float*)d_in[12];
  float* out = (float*)d_out;

  const int* src = ei;           // edge_index[0]
  const int* dst = ei + NE;      // edge_index[1]

  // ws: [ushort] xb | A | H | Wt(4)  then [int/float] sums | cnts | cnt_b | base_b | rs(+pad) | es(u16) | arena
  unsigned short* xb = (unsigned short*)d_ws;
  unsigned short* A  = xb + (size_t)NN * DF;
  unsigned short* H  = A + (size_t)NN * DF;
  unsigned short* Wt = H + (size_t)NN * DF;
  float* sums  = (float*)(Wt + (size_t)4 * DF * DF);
  int*   cnts  = (int*)(sums + NG * DF);      // 64
  int*   cnt_b = cnts + 64;                   // 128
  int*   base_b= cnt_b + 128;                 // 128
  int*   rs    = base_b + 128;                // NN+1, padded to 50004
  unsigned short* es = (unsigned short*)(rs + (NN + 4));   // NE u16, 16B-aligned
  unsigned int* arena = (unsigned int*)(es + NE);          // 98*ACAP u32

  unsigned short* Wt1a = Wt;
  unsigned short* Wt1b = Wt + DF * DF;
  unsigned short* Wt2a = Wt + 2 * DF * DF;
  unsigned short* Wt2b = Wt + 3 * DF * DF;

  const int gemm_grid   = (NN + 255) / 256;          // 196
  const int gather_grid = (NN * 64 + 255) / 256;     // 12500
  const int pool_grid   = ((NN + 31) / 32 + 3) / 4;  // 391

  // ---- prep ----
  k_cast<<<(NN * DF / 4 + 255) / 256, 256, 0, stream>>>(x, xb);
  k_prepw<<<32, 256, 0, stream>>>(W1a, W1b, W2a, W2b, Wt);
  hipMemsetAsync(sums, 0, (size_t)(NG * DF + 64 + 128) * sizeof(float), stream);
  k_part<<<PART_GRID, 256, 0, stream>>>(src, dst, cnt_b, arena);
  k_bscan<<<1, 128, 0, stream>>>(cnt_b, base_b, rs);
  k_fine<<<NBK, 256, 0, stream>>>(arena, cnt_b, base_b, rs, es);

  // ---- conv1 ----
  k_gather<<<gather_grid, 256, 0, stream>>>(xb, A, rs, es);
  k_gemm2<<<gemm_grid, 256, 0, stream>>>(A, Wt1a, b1a, Wt1b, b1b, A, NN);

  // ---- conv2 ----
  k_gather<<<gather_grid, 256, 0, stream>>>(A, H, rs, es);
  k_gemm2<<<gemm_grid, 256, 0, stream>>>(H, Wt2a, b2a, Wt2b, b2b, H, NN);

  // ---- pool + head ----
  k_pool<<<pool_grid, 256, 0, stream>>>(H, batch, sums, cnts);
  k_head<<<1, 256, 0, stream>>>(sums, cnts, Wfc, bfc, out);
}

// Round 8
// 191.606 us; speedup vs baseline: 1.0697x; 1.0697x over previous
//
#include <hip/hip_runtime.h>

#define NN 50000
#define NE 800000
#define DF 128
#define NG 64
#define NC 10
#define NBK 98            // ceil(NN/512) coarse buckets (dst>>9)
#define PART_CHUNK 4096
#define PART_GRID 196     // 196*4096 >= 800000
#define ACAP 12288        // arena capacity per bucket (avg 8163, max ~8600)
#define FINE_CAP 12288
#define RT 136            // h staging row stride (ushorts)

typedef short bf16x8 __attribute__((ext_vector_type(8)));
typedef float f32x4  __attribute__((ext_vector_type(4)));

__device__ __forceinline__ void atomAddF(float* p, float v) {
  __hip_atomic_fetch_add(p, v, __ATOMIC_RELAXED, __HIP_MEMORY_SCOPE_AGENT);
}
__device__ __forceinline__ float b2f(unsigned short u) {
  union { unsigned int i; float f; } v; v.i = (unsigned int)u << 16; return v.f;
}
__device__ __forceinline__ unsigned int f2b(float f) {
  unsigned int i = __float_as_uint(f);
  return (i + 0x7fffu + ((i >> 16) & 1u)) >> 16;
}

// ======== cast x (fp32) -> xb (bf16) ========
__global__ __launch_bounds__(256) void k_cast(const float* __restrict__ x,
                                              unsigned short* __restrict__ xb)
{
  const int i = blockIdx.x * 256 + threadIdx.x;
  if (i * 4 >= NN * DF) return;
  const float4 v = reinterpret_cast<const float4*>(x)[i];
  uint2 o;
  o.x = f2b(v.x) | (f2b(v.y) << 16);
  o.y = f2b(v.z) | (f2b(v.w) << 16);
  reinterpret_cast<uint2*>(xb)[i] = o;
}

// ======== weights -> fragment-major bf16: Wt[mat][kb][n] (bf16x8 per (kb,n) contiguous) ====
// fragment (n, kb) holds W[k = kb*8 + j][n], j=0..7
__global__ __launch_bounds__(256) void k_prepw(const float* __restrict__ W0,
                                               const float* __restrict__ W1,
                                               const float* __restrict__ W2,
                                               const float* __restrict__ W3,
                                               unsigned short* __restrict__ Wt)
{
  const int o = blockIdx.x * 256 + threadIdx.x;
  if (o >= 4 * 2048) return;
  const int mat = o >> 11;
  const float* W = (mat == 0) ? W0 : (mat == 1) ? W1 : (mat == 2) ? W2 : W3;
  const int rem = o & 2047;
  const int kb = rem >> 7;          // 0..15
  const int n  = rem & 127;         // 0..127
  unsigned int u[8];
#pragma unroll
  for (int j = 0; j < 8; ++j) u[j] = f2b(W[(size_t)(kb * 8 + j) * DF + n]);
  uint4 p;
  p.x = u[0] | (u[1] << 16);
  p.y = u[2] | (u[3] << 16);
  p.z = u[4] | (u[5] << 16);
  p.w = u[6] | (u[7] << 16);
  *reinterpret_cast<uint4*>(Wt + (size_t)mat * DF * DF + (size_t)rem * 8) = p;
}

// ---- partition edges into NBK bucket arenas (self-allocating) ----
// pack = (bucket<<25) | (dstlocal<<16) | src
__global__ __launch_bounds__(256) void k_part(const int* __restrict__ src,
                                              const int* __restrict__ dst,
                                              int* __restrict__ cnt_b,
                                              unsigned int* __restrict__ arena)
{
  __shared__ unsigned int stage[PART_CHUNK];
  __shared__ int lhist[128], lcnt[128], lcur[128], gbase[128];
  const int tid = threadIdx.x;
  const int e0  = blockIdx.x * PART_CHUNK;
  const int nE  = min(PART_CHUNK, NE - e0);

  for (int i = tid; i < 128; i += 256) lhist[i] = 0;
  __syncthreads();

  unsigned int pk[16];
  int bk[16];
#pragma unroll
  for (int i = 0; i < 16; ++i) {
    const int e = e0 + i * 256 + tid;
    if (e < NE) {
      const int d = dst[e];
      const int s = src[e];
      const int b = d >> 9;
      bk[i] = b;
      pk[i] = ((unsigned int)b << 25) | ((unsigned int)(d & 511) << 16) | (unsigned int)s;
      atomicAdd(&lhist[b], 1);
    } else {
      bk[i] = -1;
    }
  }
  __syncthreads();
  for (int i = tid; i < 128; i += 256) lcnt[i] = lhist[i];
  __syncthreads();
  for (int off = 1; off < 128; off <<= 1) {
    int v = 0;
    if (tid < 128 && tid >= off) v = lhist[tid - off];
    __syncthreads();
    if (tid < 128) lhist[tid] += v;
    __syncthreads();
  }
  if (tid < 128) lcur[tid] = lhist[tid] - lcnt[tid];
  __syncthreads();
#pragma unroll
  for (int i = 0; i < 16; ++i) {
    if (bk[i] >= 0) {
      const int pos = atomicAdd(&lcur[bk[i]], 1);
      stage[pos] = pk[i];
    }
  }
  __syncthreads();
  if (tid < NBK) {
    const int c = lcnt[tid];
    if (c > 0) gbase[tid] = atomicAdd(&cnt_b[tid], c);
  }
  __syncthreads();
  for (int idx = tid; idx < nE; idx += 256) {
    const unsigned int p = stage[idx];
    const int b = (int)(p >> 25);
    const int loff = lhist[b] - lcnt[b];
    arena[(size_t)b * ACAP + gbase[b] + (idx - loff)] = p;
  }
}

// ---- scan the 98 bucket counts -> bucket bases; rs[NN] ----
__global__ __launch_bounds__(128) void k_bscan(const int* __restrict__ cnt_b,
                                               int* __restrict__ base_b,
                                               int* __restrict__ rs)
{
  __shared__ int sm[128];
  const int t = threadIdx.x;
  const int v = (t < NBK) ? cnt_b[t] : 0;
  sm[t] = v;
  __syncthreads();
  for (int off = 1; off < 128; off <<= 1) {
    int u = (t >= off) ? sm[t - off] : 0;
    __syncthreads();
    sm[t] += u;
    __syncthreads();
  }
  base_b[t] = sm[t] - v;
  if (t == NBK - 1) rs[NN] = sm[t];   // = NE
}

// ---- per bucket: counting sort by (dstlocal, src>>13) -> rs, es(u16) ----
__global__ __launch_bounds__(256) void k_fine(const unsigned int* __restrict__ arena,
                                              const int* __restrict__ cnt_b,
                                              const int* __restrict__ base_b,
                                              int* __restrict__ rs,
                                              unsigned short* __restrict__ es)
{
  __shared__ unsigned short les[FINE_CAP];   // 24 KB
  __shared__ int bins[4096];                 // 16 KB
  __shared__ int partials[256];
  const int tid   = threadIdx.x;
  const int b     = blockIdx.x;
  const int cnt   = cnt_b[b];
  const int wbase = base_b[b];
  const int nbase = b << 9;
  const int nwin  = min(512, NN - nbase);
  const unsigned int* ap = arena + (size_t)b * ACAP;

  for (int i = tid; i < 4096; i += 256) bins[i] = 0;
  __syncthreads();
  for (int idx = tid; idx < cnt; idx += 256) {
    const unsigned int p = ap[idx];
    const int key = (int)(((p >> 16) & 511) << 3) | (int)((p & 0xffffu) >> 13);
    atomicAdd(&bins[key], 1);
  }
  __syncthreads();
  const int b16 = tid * 16;
  int sum = 0;
#pragma unroll
  for (int k = 0; k < 16; ++k) sum += bins[b16 + k];
  partials[tid] = sum;
  __syncthreads();
  for (int off = 1; off < 256; off <<= 1) {
    int u = (tid >= off) ? partials[tid - off] : 0;
    __syncthreads();
    partials[tid] += u;
    __syncthreads();
  }
  int run = partials[tid] - sum;
#pragma unroll
  for (int k = 0; k < 16; ++k) {
    const int v = bins[b16 + k];
    bins[b16 + k] = run;
    run += v;
  }
  __syncthreads();
  for (int i = tid; i < nwin; i += 256) rs[nbase + i] = wbase + bins[i << 3];
  __syncthreads();
  if (cnt <= FINE_CAP) {
    for (int idx = tid; idx < cnt; idx += 256) {
      const unsigned int p = ap[idx];
      const int key = (int)(((p >> 16) & 511) << 3) | (int)((p & 0xffffu) >> 13);
      const int pos = atomicAdd(&bins[key], 1);
      les[pos] = (unsigned short)(p & 0xffffu);
    }
    __syncthreads();
    for (int i = tid; i < cnt; i += 256) es[wbase + i] = les[i];
  } else {
    for (int idx = tid; idx < cnt; idx += 256) {
      const unsigned int p = ap[idx];
      const int key = (int)(((p >> 16) & 511) << 3) | (int)((p & 0xffffu) >> 13);
      const int pos = atomicAdd(&bins[key], 1);
      es[wbase + pos] = (unsigned short)(p & 0xffffu);
    }
  }
}

// ======== gather-aggregate (bf16): out[i] = feat[i] + sum_j feat[es_j] ========
__global__ __launch_bounds__(256) void k_gather(const unsigned short* __restrict__ feat,
                                                unsigned short* __restrict__ outp,
                                                const int* __restrict__ rs,
                                                const unsigned short* __restrict__ es)
{
  const int wid  = (blockIdx.x * 256 + threadIdx.x) >> 6;
  const int lane = threadIdx.x & 63;
  if (wid >= NN) return;
  const int beg = rs[wid];
  const int end = rs[wid + 1];
  const int off = lane * 2;

  const unsigned int self = *reinterpret_cast<const unsigned int*>(feat + (size_t)wid * DF + off);
  float ax = b2f(self & 0xffff), ay = b2f(self >> 16);
  int j = beg;
  while (j < end && (j & 3)) {
    const int s = es[j];
    const unsigned int u = *reinterpret_cast<const unsigned int*>(feat + (size_t)s * DF + off);
    ax += b2f(u & 0xffff);
    ay += b2f(u >> 16);
    ++j;
  }
  for (; j + 3 < end; j += 4) {
    const uint2 e4 = *reinterpret_cast<const uint2*>(es + j);
    const int s0 = (int)(e4.x & 0xffffu), s1 = (int)(e4.x >> 16);
    const int s2 = (int)(e4.y & 0xffffu), s3 = (int)(e4.y >> 16);
    const unsigned int u0 = *reinterpret_cast<const unsigned int*>(feat + (size_t)s0 * DF + off);
    const unsigned int u1 = *reinterpret_cast<const unsigned int*>(feat + (size_t)s1 * DF + off);
    const unsigned int u2 = *reinterpret_cast<const unsigned int*>(feat + (size_t)s2 * DF + off);
    const unsigned int u3 = *reinterpret_cast<const unsigned int*>(feat + (size_t)s3 * DF + off);
    ax += b2f(u0 & 0xffff) + b2f(u1 & 0xffff) + b2f(u2 & 0xffff) + b2f(u3 & 0xffff);
    ay += b2f(u0 >> 16)    + b2f(u1 >> 16)    + b2f(u2 >> 16)    + b2f(u3 >> 16);
  }
  for (; j < end; ++j) {
    const int s = es[j];
    const unsigned int u = *reinterpret_cast<const unsigned int*>(feat + (size_t)s * DF + off);
    ax += b2f(u & 0xffff);
    ay += b2f(u >> 16);
  }
  const unsigned int o = f2b(ax) | (f2b(ay) << 16);
  *reinterpret_cast<unsigned int*>(outp + (size_t)wid * DF + off) = o;
}

// ======== fused double GEMM: out = relu(relu(A@Wa+ba)@Wb+bb), bf16 MFMA ========
// 512 threads = 8 waves, 16 rows/wave, 128 rows/block, grid 391.
// Wa fragments in VGPRs (fragment-major global), Wb staged linearly into LDS,
// h bounced through wave-private LDS (RT=136 stride, ~conflict-free).
__global__ __launch_bounds__(512) void k_gemm2(const unsigned short* __restrict__ Ab,
                                               const unsigned short* __restrict__ Wta,
                                               const float* __restrict__ ba,
                                               const unsigned short* __restrict__ Wtb,
                                               const float* __restrict__ bb,
                                               unsigned short* __restrict__ outb, int M)
{
  __shared__ unsigned short WbL[2048 * 8];      // 32 KB, fragment-major [kb*128+n]
  __shared__ unsigned short hL[8][16 * RT];     // 34 KB
  const int tid  = threadIdx.x;
  const int lane = tid & 63;
  const int w    = tid >> 6;          // 0..7
  const int col  = lane & 15;
  const int kq   = lane >> 4;         // 0..3

  // stage Wb: straight 32 KB copy (coalesced global, linear LDS)
  for (int i = tid; i < 2048; i += 512)
    *reinterpret_cast<uint4*>(&WbL[i * 8]) =
        *reinterpret_cast<const uint4*>(&Wtb[(size_t)i * 8]);

  // Wa fragments resident in VGPRs (fragment-major: (kb*128 + n)*8)
  bf16x8 wfa[8][4];
#pragma unroll
  for (int nf = 0; nf < 8; ++nf)
#pragma unroll
    for (int s = 0; s < 4; ++s)
      wfa[nf][s] = *reinterpret_cast<const bf16x8*>(
          Wta + ((size_t)(s * 4 + kq) * 128 + nf * 16 + col) * 8);

  float4 bva[8], bvb[8];
#pragma unroll
  for (int nf = 0; nf < 8; ++nf) {
    bva[nf] = *reinterpret_cast<const float4*>(ba + nf * 16 + kq * 4);
    bvb[nf] = *reinterpret_cast<const float4*>(bb + nf * 16 + kq * 4);
  }

  __syncthreads();

  unsigned short* hw = &hL[w][0];
  const int m   = blockIdx.x * 128 + w * 16 + col;
  const int mld = (m < M) ? m : (M - 1);

  bf16x8 bc[4];
#pragma unroll
  for (int s = 0; s < 4; ++s)
    bc[s] = *reinterpret_cast<const bf16x8*>(Ab + (size_t)mld * DF + s * 32 + kq * 8);

  // ---- GEMM1 ----
  f32x4 acc[8];
#pragma unroll
  for (int nf = 0; nf < 8; ++nf) acc[nf] = (f32x4){0.f, 0.f, 0.f, 0.f};
#pragma unroll
  for (int s = 0; s < 4; ++s)
#pragma unroll
    for (int nf = 0; nf < 8; ++nf)
      acc[nf] = __builtin_amdgcn_mfma_f32_16x16x32_bf16(wfa[nf][s], bc[s], acc[nf], 0, 0, 0);

  // ---- bias_a + relu -> bf16 -> wave-private LDS ----
#pragma unroll
  for (int nf = 0; nf < 8; ++nf) {
    uint2 pk;
    pk.x = f2b(fmaxf(acc[nf][0] + bva[nf].x, 0.f)) | (f2b(fmaxf(acc[nf][1] + bva[nf].y, 0.f)) << 16);
    pk.y = f2b(fmaxf(acc[nf][2] + bva[nf].z, 0.f)) | (f2b(fmaxf(acc[nf][3] + bva[nf].w, 0.f)) << 16);
    *reinterpret_cast<uint2*>(&hw[col * RT + nf * 16 + kq * 4]) = pk;
  }
  asm volatile("s_waitcnt lgkmcnt(0)" ::: "memory");
  __builtin_amdgcn_sched_barrier(0);

  // ---- GEMM2 ----
  f32x4 acc2[8];
#pragma unroll
  for (int nf = 0; nf < 8; ++nf) acc2[nf] = (f32x4){0.f, 0.f, 0.f, 0.f};
#pragma unroll
  for (int s = 0; s < 4; ++s) {
    const bf16x8 hb = *reinterpret_cast<const bf16x8*>(&hw[col * RT + s * 32 + kq * 8]);
#pragma unroll
    for (int nf = 0; nf < 8; ++nf) {
      const bf16x8 wb = *reinterpret_cast<const bf16x8*>(
          &WbL[((s * 4 + kq) * 128 + nf * 16 + col) * 8]);
      acc2[nf] = __builtin_amdgcn_mfma_f32_16x16x32_bf16(wb, hb, acc2[nf], 0, 0, 0);
    }
  }
  if (m < M) {
#pragma unroll
    for (int nf = 0; nf < 8; ++nf) {
      ushort4 p;
      p.x = (unsigned short)f2b(fmaxf(acc2[nf][0] + bvb[nf].x, 0.f));
      p.y = (unsigned short)f2b(fmaxf(acc2[nf][1] + bvb[nf].y, 0.f));
      p.z = (unsigned short)f2b(fmaxf(acc2[nf][2] + bvb[nf].z, 0.f));
      p.w = (unsigned short)f2b(fmaxf(acc2[nf][3] + bvb[nf].w, 0.f));
      *reinterpret_cast<ushort4*>(outb + (size_t)m * DF + nf * 16 + kq * 4) = p;
    }
  }
}

// ======== segment-mean pooling ========
__global__ __launch_bounds__(256) void k_pool(const unsigned short* __restrict__ h,
                                              const int* __restrict__ batch,
                                              float* __restrict__ sums,
                                              int* __restrict__ cnts)
{
  const int wv   = (blockIdx.x * 256 + threadIdx.x) >> 6;
  const int lane = threadIdx.x & 63;
  const int n0 = wv * 32;
  if (n0 >= NN) return;
  const int n1 = min(n0 + 32, NN);
  const int off = lane * 2;

  const int gfirst = batch[n0];
  const int glast  = batch[n1 - 1];
  float ax = 0.f, ay = 0.f;

  if (gfirst == glast) {
#pragma unroll 4
    for (int i = n0; i < n1; ++i) {
      const unsigned int u = *reinterpret_cast<const unsigned int*>(h + (size_t)i * DF + off);
      ax += b2f(u & 0xffff);
      ay += b2f(u >> 16);
    }
    atomAddF(&sums[gfirst * DF + off],     ax);
    atomAddF(&sums[gfirst * DF + off + 1], ay);
    if (lane == 0) atomicAdd(&cnts[gfirst], n1 - n0);
  } else {
    int g = gfirst, cnt = 0;
    for (int i = n0; i < n1; ++i) {
      const int gi = batch[i];
      if (gi != g) {
        atomAddF(&sums[g * DF + off],     ax);
        atomAddF(&sums[g * DF + off + 1], ay);
        if (lane == 0) atomicAdd(&cnts[g], cnt);
        ax = 0.f; ay = 0.f; cnt = 0; g = gi;
      }
      const unsigned int u = *reinterpret_cast<const unsigned int*>(h + (size_t)i * DF + off);
      ax += b2f(u & 0xffff);
      ay += b2f(u >> 16);
      ++cnt;
    }
    atomAddF(&sums[g * DF + off],     ax);
    atomAddF(&sums[g * DF + off + 1], ay);
    if (lane == 0) atomicAdd(&cnts[g], cnt);
  }
}

// ======== head ========
__global__ __launch_bounds__(256) void k_head(const float* __restrict__ sums,
                                              const int* __restrict__ cnts,
                                              const float* __restrict__ Wfc,
                                              const float* __restrict__ bfc,
                                              float* __restrict__ out)
{
  for (int o = threadIdx.x; o < NG * NC; o += 256) {
    const int g = o / NC, c = o % NC;
    const float inv = 1.f / fmaxf((float)cnts[g], 1.f);
    float z = bfc[c];
    for (int k = 0; k < DF; ++k)
      z = fmaf(sums[g * DF + k] * inv, Wfc[k * NC + c], z);
    out[o] = 1.f / (1.f + expf(-z));
  }
}

extern "C" void kernel_launch(void* const* d_in, const int* in_sizes, int n_in,
                              void* d_out, int out_size, void* d_ws, size_t ws_size,
                              hipStream_t stream)
{
  const float* x   = (const float*)d_in[0];
  const int*   ei  = (const int*)d_in[1];
  const int* batch = (const int*)d_in[2];
  const float* W1a = (const float*)d_in[3];
  const float* b1a = (const float*)d_in[4];
  const float* W1b = (const float*)d_in[5];
  const float* b1b = (const float*)d_in[6];
  const float* W2a = (const float*)d_in[7];
  const float* b2a = (const float*)d_in[8];
  const float* W2b = (const float*)d_in[9];
  const float* b2b = (const float*)d_in[10];
  const float* Wfc = (const float*)d_in[11];
  const float* bfc = (const float*)d_in[12];
  float* out = (float*)d_out;

  const int* src = ei;           // edge_index[0]
  const int* dst = ei + NE;      // edge_index[1]

  // ws: [ushort] xb | A | H | Wt(4)  then [int/float] sums | cnts | cnt_b | base_b | rs(+pad) | es(u16) | arena
  unsigned short* xb = (unsigned short*)d_ws;
  unsigned short* A  = xb + (size_t)NN * DF;
  unsigned short* H  = A + (size_t)NN * DF;
  unsigned short* Wt = H + (size_t)NN * DF;
  float* sums  = (float*)(Wt + (size_t)4 * DF * DF);
  int*   cnts  = (int*)(sums + NG * DF);      // 64
  int*   cnt_b = cnts + 64;                   // 128
  int*   base_b= cnt_b + 128;                 // 128
  int*   rs    = base_b + 128;                // NN+1, padded
  unsigned short* es = (unsigned short*)(rs + (NN + 4));   // NE u16
  unsigned int* arena = (unsigned int*)(es + NE);          // 98*ACAP u32

  unsigned short* Wt1a = Wt;
  unsigned short* Wt1b = Wt + DF * DF;
  unsigned short* Wt2a = Wt + 2 * DF * DF;
  unsigned short* Wt2b = Wt + 3 * DF * DF;

  const int gemm_grid   = (NN + 127) / 128;          // 391
  const int gather_grid = (NN * 64 + 255) / 256;     // 12500
  const int pool_grid   = ((NN + 31) / 32 + 3) / 4;  // 391

  // ---- prep ----
  k_cast<<<(NN * DF / 4 + 255) / 256, 256, 0, stream>>>(x, xb);
  k_prepw<<<32, 256, 0, stream>>>(W1a, W1b, W2a, W2b, Wt);
  hipMemsetAsync(sums, 0, (size_t)(NG * DF + 64 + 128) * sizeof(float), stream);
  k_part<<<PART_GRID, 256, 0, stream>>>(src, dst, cnt_b, arena);
  k_bscan<<<1, 128, 0, stream>>>(cnt_b, base_b, rs);
  k_fine<<<NBK, 256, 0, stream>>>(arena, cnt_b, base_b, rs, es);

  // ---- conv1 ----
  k_gather<<<gather_grid, 256, 0, stream>>>(xb, A, rs, es);
  k_gemm2<<<gemm_grid, 512, 0, stream>>>(A, Wt1a, b1a, Wt1b, b1b, A, NN);

  // ---- conv2 ----
  k_gather<<<gather_grid, 256, 0, stream>>>(A, H, rs, es);
  k_gemm2<<<gemm_grid, 512, 0, stream>>>(H, Wt2a, b2a, Wt2b, b2b, H, NN);

  // ---- pool + head ----
  k_pool<<<pool_grid, 256, 0, stream>>>(H, batch, sums, cnts);
  k_head<<<1, 256, 0, stream>>>(sums, cnts, Wfc, bfc, out);
}